// Round 6
// baseline (314.977 us; speedup 1.0000x reference)
//
#include <hip/hip_runtime.h>
#include <hip/hip_bf16.h>

// VeRA: out = SCALE * d_B[o] * ((x @ (d_A*A)^T) @ B^T)
// GEMM1 (split-K=4): part[s] = x @ Ab^T over K-chunk  (M=8192,N=256,K=1024 each)
// reduce: t = bf16(sum_s part[s])
// GEMM2: out = SCALE*d_B * (t @ Bb^T)  (M=8192,N=4096,K=256)
//
// R6: deepen the pipeline. R4/R5's 2-deep ring gave each tile only ~1 compute
// phase (~250-400cyc) of in-flight time vs ~900cyc cold-load latency ->
// ~400-900cyc exposed per k-step (matches 7% MfmaUtil). gemm1: DEPTH=3 ring
// (window = 2 phases x 2 resident blocks); gemm2: DEPTH=4, 3 tiles in flight.
// Everything else (geometry, swizzles, XCD maps, numerics) identical to R5.

#define SCALE_F 0.125f
#define M_TOT 8192
#define K_IN 4096
#define RANK 256
#define N_OUT 4096
#define S_SPLIT 4
#define KC 1024   // K_IN / S_SPLIT

typedef __bf16 bf16_t;
typedef __bf16 bf16x8 __attribute__((ext_vector_type(8)));
typedef __bf16 bf16x4 __attribute__((ext_vector_type(4)));
typedef float f32x4 __attribute__((ext_vector_type(4)));

typedef __attribute__((address_space(3))) unsigned int lds_u32_t;
typedef const __attribute__((address_space(1))) unsigned int glob_u32_t;

__device__ __forceinline__ void async16(const void* g, void* l) {
    __builtin_amdgcn_global_load_lds((glob_u32_t*)g, (lds_u32_t*)l, 16, 0, 0);
}

// ---- convert A (fold d_A) and B to bf16, fused ----
__global__ __launch_bounds__(256) void conv_AB(const float* __restrict__ A,
                                               const float* __restrict__ dA,
                                               const float* __restrict__ B,
                                               bf16_t* __restrict__ Ab,
                                               bf16_t* __restrict__ Bb) {
    int b = blockIdx.x;
    if (b < 1024) {
        int idx = b * 256 + threadIdx.x;
        float4 v = ((const float4*)A)[idx];
        float s = dA[idx >> 10];
        bf16x4 o;
        o.x = (bf16_t)(v.x * s); o.y = (bf16_t)(v.y * s);
        o.z = (bf16_t)(v.z * s); o.w = (bf16_t)(v.w * s);
        ((bf16x4*)Ab)[idx] = o;
    } else {
        int idx = (b - 1024) * 256 + threadIdx.x;
        float4 v = ((const float4*)B)[idx];
        bf16x4 o;
        o.x = (bf16_t)v.x; o.y = (bf16_t)v.y;
        o.z = (bf16_t)v.z; o.w = (bf16_t)v.w;
        ((bf16x4*)Bb)[idx] = o;
    }
}

// ---- GEMM1: part[z][8192][256] = x(fp32) @ Ab^T over K-chunk z ----
// BM=64, BN=256 (x staged once), BK=32, DEPTH=3. 512 blocks, 2/CU (72 KB).
// Block map: xcd = wg&7 -> z = xcd>>1; A-chunk (0.5 MB) L2-resident per
// XCD-pair. 4 waves 2x2, wave tile 32x128: 16 MFMA/k-step.
// Ring: 3 tiles staged, steady-state wait vmcnt(12) (6 async16/stage);
// raw s_barrier, no drain. sX raw f32 (cvt at read); sA bf16.
__global__ __launch_bounds__(256, 2) void gemm1(const float* __restrict__ x,
                                                const bf16_t* __restrict__ Ab,
                                                bf16_t* __restrict__ part) {
    __shared__ float  sXf[3][64 * 32];   // 8 KB each
    __shared__ bf16_t sA[3][256 * 32];   // 16 KB each; total 72 KB
    const int tid = threadIdx.x;
    const int lane = tid & 63, wave = tid >> 6;
    const int wm = wave >> 1, wn = wave & 1;
    const int l15 = lane & 15, quad = lane >> 4;

    const int wg  = blockIdx.x;
    const int xcd = wg & 7;
    const int z   = xcd >> 1;
    const int m   = (wg >> 3) | ((xcd & 1) << 6);   // [0,128)
    const int bm  = m * 64;
    const int k0  = z * KC;

    f32x4 acc[2][8];
    const f32x4 zero = {0.f, 0.f, 0.f, 0.f};
    #pragma unroll
    for (int i = 0; i < 2; i++)
        #pragma unroll
        for (int j = 0; j < 8; j++) acc[i][j] = zero;

    // 6 async16 per thread per stage (2 sX + 4 sA)
    auto stage = [&](int b, int ts) {
        const int kk = k0 + ts * 32;
        #pragma unroll
        for (int c = 0; c < 2; c++) {          // sX: 64 rows x 8 slots of 4 f32
            int idx = c * 256 + tid;
            int row = idx >> 3, sl = idx & 7;
            async16(&x[(size_t)(bm + row) * K_IN + kk + ((sl ^ (row & 7)) << 2)],
                    &sXf[b][idx * 4]);
        }
        #pragma unroll
        for (int c = 0; c < 4; c++) {          // sA: 256 rows x 4 slots of 8 bf16
            int idx = c * 256 + tid;
            int row = idx >> 2, sl = idx & 3;
            async16(&Ab[(size_t)row * K_IN + kk + ((sl ^ ((row >> 1) & 3)) << 3)],
                    &sA[b][idx * 8]);
        }
    };
    auto compute = [&](int b) {
        bf16x8 af[2], bfr[8];
        #pragma unroll
        for (int i = 0; i < 2; i++) {
            int row = wm * 32 + i * 16 + l15;
            f32x4 v0 = *(const f32x4*)&sXf[b][row * 32 + ((((quad << 1) | 0) ^ (row & 7)) << 2)];
            f32x4 v1 = *(const f32x4*)&sXf[b][row * 32 + ((((quad << 1) | 1) ^ (row & 7)) << 2)];
            bf16x8 t;
            #pragma unroll
            for (int e = 0; e < 4; e++) { t[e] = (bf16_t)v0[e]; t[e + 4] = (bf16_t)v1[e]; }
            af[i] = t;
        }
        #pragma unroll
        for (int j = 0; j < 8; j++) {
            int row = wn * 128 + j * 16 + l15;
            bfr[j] = *(const bf16x8*)&sA[b][row * 32 + ((quad ^ ((row >> 1) & 3)) << 3)];
        }
        // swapped operands: lane&15 = m-row, quad*4+r = n-col
        #pragma unroll
        for (int i = 0; i < 2; i++)
            #pragma unroll
            for (int j = 0; j < 8; j++)
                acc[i][j] = __builtin_amdgcn_mfma_f32_16x16x32_bf16(bfr[j], af[i], acc[i][j], 0, 0, 0);
    };

    const int NT = KC / 32;   // 32 k-steps
    stage(0, 0);
    stage(1, 1);
    stage(2, 2);              // 18 loads outstanding (3 tiles)
    int cur = 0;
    for (int t = 0; t < NT - 3; ++t) {
        asm volatile("s_waitcnt vmcnt(12)" ::: "memory");  // tile t landed; t+1,t+2 in flight
        __builtin_amdgcn_s_barrier();
        compute(cur);
        __builtin_amdgcn_s_barrier();                      // all waves done reading cur
        stage(cur, t + 3);                                 // refill; stays in flight
        cur = (cur == 2) ? 0 : cur + 1;
    }
    // tails: t = NT-3, NT-2, NT-1 with outstanding 12 -> 6 -> 0
    asm volatile("s_waitcnt vmcnt(12)" ::: "memory");
    __builtin_amdgcn_s_barrier();
    compute(cur);
    __builtin_amdgcn_s_barrier();
    cur = (cur == 2) ? 0 : cur + 1;
    asm volatile("s_waitcnt vmcnt(6)" ::: "memory");
    __builtin_amdgcn_s_barrier();
    compute(cur);
    __builtin_amdgcn_s_barrier();
    cur = (cur == 2) ? 0 : cur + 1;
    asm volatile("s_waitcnt vmcnt(0)" ::: "memory");
    __builtin_amdgcn_s_barrier();
    compute(cur);

    bf16_t* p = part + (size_t)z * (M_TOT * RANK);
    #pragma unroll
    for (int i = 0; i < 2; i++) {
        int row = bm + wm * 32 + i * 16 + l15;
        #pragma unroll
        for (int j = 0; j < 8; j++) {
            int col = wn * 128 + j * 16 + quad * 4;
            bf16x4 o;
            #pragma unroll
            for (int r = 0; r < 4; r++) o[r] = (bf16_t)acc[i][j][r];
            *(bf16x4*)&p[(size_t)row * RANK + col] = o;
        }
    }
}

// ---- reduce: t = bf16(sum_z part[z]) ----
__global__ __launch_bounds__(256) void reduce_t(const bf16_t* __restrict__ part,
                                                bf16_t* __restrict__ t) {
    int i = (blockIdx.x * 256 + threadIdx.x) * 8;
    float s[8] = {0.f, 0.f, 0.f, 0.f, 0.f, 0.f, 0.f, 0.f};
    #pragma unroll
    for (int z = 0; z < S_SPLIT; z++) {
        bf16x8 v = *(const bf16x8*)&part[(size_t)z * M_TOT * RANK + i];
        #pragma unroll
        for (int e = 0; e < 8; e++) s[e] += (float)v[e];
    }
    bf16x8 o;
    #pragma unroll
    for (int e = 0; e < 8; e++) o[e] = (bf16_t)s[e];
    *(bf16x8*)&t[i] = o;
}

// ---- GEMM2: out[8192][4096] = SCALE*dB * (t @ Bb^T) ----
// BM=128, BN=64, BK=32, 8 k-steps, DEPTH=4 (3 tiles in flight). 4096 blocks;
// 2-D XCD tiling (t-slice + B-slice L2-resident). 48 KB LDS -> 3 resident.
// 4 waves 2x2, wave tile 64x32. Steady-state wait vmcnt(6) (3 async16/stage).
__global__ __launch_bounds__(256, 3) void gemm2(const bf16_t* __restrict__ t,
                                                const bf16_t* __restrict__ Bb,
                                                const float* __restrict__ dB,
                                                float* __restrict__ out) {
    __shared__ bf16_t sT[4][128 * 32];   // 8 KB each
    __shared__ bf16_t sB[4][64 * 32];    // 4 KB each; total 48 KB
    const int tid = threadIdx.x;
    const int lane = tid & 63, wave = tid >> 6;
    const int wm = wave >> 1, wn = wave & 1;
    const int l15 = lane & 15, quad = lane >> 4;

    const int wg  = blockIdx.x;
    const int xcd = wg & 7;
    const int w   = wg >> 3;                       // [0,512)
    const int mb  = (xcd & 1) * 32 + (w & 31);     // [0,64)
    const int nb  = (xcd >> 1) * 16 + (w >> 5);    // [0,64)
    const int bm  = mb * 128;
    const int bn  = nb * 64;

    f32x4 acc[4][2];
    const f32x4 zero = {0.f, 0.f, 0.f, 0.f};
    #pragma unroll
    for (int i = 0; i < 4; i++)
        #pragma unroll
        for (int j = 0; j < 2; j++) acc[i][j] = zero;

    // 3 async16 per thread per stage (2 sT + 1 sB)
    auto stage = [&](int b, int ts) {
        const int kt = ts * 32;
        #pragma unroll
        for (int c = 0; c < 2; c++) {          // sT: 128 rows x 4 slots
            int idx = c * 256 + tid;
            int row = idx >> 2, sl = idx & 3;
            async16(&t[(size_t)(bm + row) * RANK + kt + ((sl ^ ((row >> 1) & 3)) << 3)],
                    &sT[b][idx * 8]);
        }
        {                                      // sB: 64 rows x 4 slots
            int row = tid >> 2, sl = tid & 3;
            async16(&Bb[(size_t)(bn + row) * RANK + kt + ((sl ^ ((row >> 1) & 3)) << 3)],
                    &sB[b][tid * 8]);
        }
    };
    auto compute = [&](int b) {
        bf16x8 af[4], bfr[2];
        #pragma unroll
        for (int i = 0; i < 4; i++) {
            int row = wm * 64 + i * 16 + l15;
            af[i] = *(const bf16x8*)&sT[b][row * 32 + ((quad ^ ((row >> 1) & 3)) << 3)];
        }
        #pragma unroll
        for (int j = 0; j < 2; j++) {
            int row = wn * 32 + j * 16 + l15;
            bfr[j] = *(const bf16x8*)&sB[b][row * 32 + ((quad ^ ((row >> 1) & 3)) << 3)];
        }
        #pragma unroll
        for (int i = 0; i < 4; i++)
            #pragma unroll
            for (int j = 0; j < 2; j++)
                acc[i][j] = __builtin_amdgcn_mfma_f32_16x16x32_bf16(bfr[j], af[i], acc[i][j], 0, 0, 0);
    };

    const int NT = RANK / 32;   // 8 k-steps
    stage(0, 0);
    stage(1, 1);
    stage(2, 2);                // 9 outstanding (3 tiles)
    #pragma unroll
    for (int t = 0; t < NT - 3; ++t) {
        asm volatile("s_waitcnt vmcnt(6)" ::: "memory");   // tile t landed
        __builtin_amdgcn_s_barrier();
        compute(t & 3);
        __builtin_amdgcn_s_barrier();
        stage((t + 3) & 3, t + 3);
    }
    // tails: t = NT-3, NT-2, NT-1 with outstanding 6 -> 3 -> 0
    asm volatile("s_waitcnt vmcnt(6)" ::: "memory");
    __builtin_amdgcn_s_barrier();
    compute((NT - 3) & 3);
    __builtin_amdgcn_s_barrier();
    asm volatile("s_waitcnt vmcnt(3)" ::: "memory");
    __builtin_amdgcn_s_barrier();
    compute((NT - 2) & 3);
    __builtin_amdgcn_s_barrier();
    asm volatile("s_waitcnt vmcnt(0)" ::: "memory");
    __builtin_amdgcn_s_barrier();
    compute((NT - 1) & 3);

    #pragma unroll
    for (int i = 0; i < 4; i++) {
        int row = bm + wm * 64 + i * 16 + l15;
        #pragma unroll
        for (int j = 0; j < 2; j++) {
            int col = bn + wn * 32 + j * 16 + quad * 4;
            f32x4 db = *(const f32x4*)&dB[col];
            f32x4 o;
            #pragma unroll
            for (int r = 0; r < 4; r++) o[r] = db[r] * SCALE_F * acc[i][j][r];
            *(f32x4*)&out[(size_t)row * N_OUT + col] = o;
        }
    }
}

extern "C" void kernel_launch(void* const* d_in, const int* in_sizes, int n_in,
                              void* d_out, int out_size, void* d_ws, size_t ws_size,
                              hipStream_t stream) {
    const float* x  = (const float*)d_in[0];
    const float* A  = (const float*)d_in[1];
    const float* B  = (const float*)d_in[2];
    const float* dA = (const float*)d_in[3];
    const float* dB = (const float*)d_in[4];
    float* out = (float*)d_out;

    char* ws = (char*)d_ws;
    bf16_t* Ab   = (bf16_t*)ws;                       // 2 MB
    bf16_t* Bb   = (bf16_t*)(ws + (1u << 21));        // 2 MB
    bf16_t* tt   = (bf16_t*)(ws + (1u << 22));        // 4 MB
    bf16_t* part = (bf16_t*)(ws + (1u << 23));        // 4 * 4 MB = 16 MB

    conv_AB<<<2048, 256, 0, stream>>>(A, dA, B, Ab, Bb);
    gemm1<<<512, 256, 0, stream>>>(x, Ab, part);
    reduce_t<<<1024, 256, 0, stream>>>(part, tt);
    gemm2<<<4096, 256, 0, stream>>>(tt, Bb, dB, out);
}